// Round 4
// baseline (418.101 us; speedup 1.0000x reference)
//
#include <hip/hip_runtime.h>

// MMSE-PIC detector: B=32768, M=16, S=8, QAM16 Gray, 2 iterations.
// Round 4: 2 batches (2 independent waves) per 128-thread workgroup to break
// the 16-workgroup/CU occupancy cap; forward-only unnormalized elimination
// (S = L D L^H => RHS becomes L^-1[h|y]; scale rows by rsqrt(d) to get the
// whitened W = L_chol^-1 [h|y]); Gram g = Wh^H Wh, y_mf = Wh^H Wy (no back-
// substitution, no original-h copy needed). log1pf -> __logf(1+t).

#define EPS_F 1e-4f
#define INV_SQRT10 0.31622776601683794f
#define WSYNC() __builtin_amdgcn_wave_barrier()

__device__ __forceinline__ float rcpf(float x) { return __builtin_amdgcn_rcpf(x); }
__device__ __forceinline__ float rsqf(float x) { return __builtin_amdgcn_rsqf(x); }
__device__ __forceinline__ float pt_re(int p) {
    return (1.0f - 2.0f * (float)((p >> 3) & 1)) * (1.0f + 2.0f * (float)((p >> 1) & 1)) * INV_SQRT10;
}
__device__ __forceinline__ float pt_im(int p) {
    return (1.0f - 2.0f * (float)((p >> 2) & 1)) * (1.0f + 2.0f * (float)(p & 1)) * INV_SQRT10;
}

__global__ __launch_bounds__(128, 8)
void mmse_pic_kernel(const float* __restrict__ y_re, const float* __restrict__ y_im,
                     const float* __restrict__ h_re, const float* __restrict__ h_im,
                     const float* __restrict__ prior,
                     const float* __restrict__ s_re, const float* __restrict__ s_im,
                     float* __restrict__ out)
{
    const int lane = threadIdx.x & 63;
    const int w    = threadIdx.x >> 6;            // wave id in block = sub-batch
    const int b    = blockIdx.x * 2 + w;
    const size_t bs = (size_t)b;

    __shared__ float2 Sc[2][16][28];   // [S(0-15) | h(16-23) | y(24)] -> W after elim+scale
    __shared__ float2 xc_[2][8];
    __shared__ float2 ymc_[2][8];
    __shared__ float  vx_[2][8], ne_[2][8];
    __shared__ float  lsig[2][64];
    __shared__ float  logit_[2][8][20];
    __shared__ float  llrD_[2][8][4];

    // ---- load (vectorized, interleave re/im into float2) ----
    {
        const float4* pr4 = (const float4*)(s_re + bs * 256);
        const float4* pi4 = (const float4*)(s_im + bs * 256);
        float4 vr = pr4[lane], vi = pi4[lane];
        int r = lane >> 2, c0 = (lane & 3) << 2;
        Sc[w][r][c0+0] = make_float2(vr.x, vi.x);
        Sc[w][r][c0+1] = make_float2(vr.y, vi.y);
        Sc[w][r][c0+2] = make_float2(vr.z, vi.z);
        Sc[w][r][c0+3] = make_float2(vr.w, vi.w);
        if (lane < 32) {
            const float4* hr4 = (const float4*)(h_re + bs * 128);
            const float4* hi4 = (const float4*)(h_im + bs * 128);
            float4 hr = hr4[lane], hi = hi4[lane];
            int row = lane >> 1, col = 16 + ((lane & 1) << 2);
            Sc[w][row][col+0] = make_float2(hr.x, hi.x);
            Sc[w][row][col+1] = make_float2(hr.y, hi.y);
            Sc[w][row][col+2] = make_float2(hr.z, hi.z);
            Sc[w][row][col+3] = make_float2(hr.w, hi.w);
        }
        if (lane < 16) Sc[w][lane][24] = make_float2(y_re[bs*16+lane], y_im[bs*16+lane]);
        if (lane < 32) ((float*)llrD_[w])[lane] = prior[bs*32 + lane];
    }
    WSYNC();

    // ---- forward-only unnormalized elimination on [S | h y] ----
    // After step k, rows i>k: row_i -= (S[i][k]/d_k) row_k  (cols k+1..24).
    // RHS rows become L^-1 [h|y]; pivots d_k real (S HPD).
    {
        const int j0 = lane & 15;
        const int r4 = lane >> 4;
        for (int k = 0; k < 15; ++k) {
            float invd = rcpf(Sc[w][k][k].x);
            int j1 = k + 1 + j0, j2 = j1 + 16;
            float2 rk0 = make_float2(0.f, 0.f), rk1 = make_float2(0.f, 0.f);
            if (j1 < 25) rk0 = Sc[w][k][j1];
            const bool blk2 = (k < 8);
            if (blk2 && j2 < 25) rk1 = Sc[w][k][j2];
            const int pmin = (k + 1) >> 2;          // skip row-blocks entirely <= k
            for (int p = pmin; p < 4; ++p) {
                int i = (p << 2) + r4;
                float2 aik = Sc[w][i][k];
                float mr = aik.x * invd, mi = aik.y * invd;
                if (i <= k) { mr = 0.f; mi = 0.f; }
                if (j1 < 25) {
                    float2 a = Sc[w][i][j1];
                    a.x -= mr*rk0.x - mi*rk0.y;
                    a.y -= mr*rk0.y + mi*rk0.x;
                    Sc[w][i][j1] = a;
                }
                if (blk2 && j2 < 25) {
                    float2 a = Sc[w][i][j2];
                    a.x -= mr*rk1.x - mi*rk1.y;
                    a.y -= mr*rk1.y + mi*rk1.x;
                    Sc[w][i][j2] = a;
                }
            }
            WSYNC();
        }
    }
    // ---- scale RHS rows by rsqrt(d_m): W = D^-1/2 L^-1 [h|y] (= whitened) ----
    {
        int r2 = lane >> 2, c = lane & 3;
        float irs = rsqf(Sc[w][r2][r2].x);
        float2 v0 = Sc[w][r2][16 + c];
        Sc[w][r2][16 + c] = make_float2(v0.x*irs, v0.y*irs);
        float2 v1 = Sc[w][r2][20 + c];
        Sc[w][r2][20 + c] = make_float2(v1.x*irs, v1.y*irs);
        if (c == 0) {
            float2 v2 = Sc[w][r2][24];
            Sc[w][r2][24] = make_float2(v2.x*irs, v2.y*irs);
        }
    }
    WSYNC();

    // ---- Gram g[i][j] = (Wh^H Wh)[i][j] (1 entry/lane), y_mf = Wh^H Wy ----
    const int s = lane >> 3, u = lane & 7;
    float g_re = 0.f, g_im = 0.f, ym_r = 0.f, ym_i = 0.f;
    #pragma unroll
    for (int m = 0; m < 16; ++m) {
        float2 a  = Sc[w][m][16 + s];
        float2 x  = Sc[w][m][16 + u];
        float2 xy = Sc[w][m][24];
        g_re += a.x*x.x + a.y*x.y;      // conj(a)*x
        g_im += a.x*x.y - a.y*x.x;
        ym_r += a.x*xy.x + a.y*xy.y;
        ym_i += a.x*xy.y - a.y*xy.x;
    }
    if (u == 0) ymc_[w][s] = make_float2(ym_r, ym_i);
    WSYNC();

    const float pr = pt_re(u), pi2 = pt_im(u), pe = pr*pr + pi2*pi2;  // pt(u+8) = (-pr, pi2)
    float llr_a_reg = 0.f;

    for (int it = 0; it < 2; ++it) {
        // log-sigmoid table: one distinct value per lane
        {
            int ts = lane >> 3, tk = (lane >> 1) & 3, sg = lane & 1;
            float v = llrD_[w][ts][tk];
            float x = sg ? v : -v;
            lsig[w][lane] = fminf(x, 0.f) - __logf(1.0f + __expf(-fabsf(x)));
        }
        if (lane < 32) llr_a_reg = ((float*)llrD_[w])[lane];
        WSYNC();
        // symbol logits for p=u (l0) and p=u+8 (l1), in registers
        int base = s << 3;
        float lc = lsig[w][base | 2 | ((u >> 2) & 1)]
                 + lsig[w][base | 4 | ((u >> 1) & 1)]
                 + lsig[w][base | 6 | (u & 1)];
        float l0 = lc + lsig[w][base];
        float l1 = lc + lsig[w][base | 1];
        // moments: butterfly over the 8 lanes of stream s
        {
            float mx = fmaxf(l0, l1);
            mx = fmaxf(mx, __shfl_xor(mx, 1));
            mx = fmaxf(mx, __shfl_xor(mx, 2));
            mx = fmaxf(mx, __shfl_xor(mx, 4));
            float w0 = __expf(l0 - mx), w1 = __expf(l1 - mx);
            float a = w0 + w1, dw = w0 - w1;
            float se = a, mr = dw * pr, mi = a * pi2, e2 = a * pe;
            se += __shfl_xor(se,1); mr += __shfl_xor(mr,1); mi += __shfl_xor(mi,1); e2 += __shfl_xor(e2,1);
            se += __shfl_xor(se,2); mr += __shfl_xor(mr,2); mi += __shfl_xor(mi,2); e2 += __shfl_xor(e2,2);
            se += __shfl_xor(se,4); mr += __shfl_xor(mr,4); mi += __shfl_xor(mi,4); e2 += __shfl_xor(e2,4);
            if (u == 0) {
                float inv = rcpf(se);
                float mxr = mr*inv, mxi = mi*inv;
                xc_[w][s] = make_float2(mxr, mxi);
                vx_[w][s] = e2*inv - (mxr*mxr + mxi*mxi);
            }
        }
        WSYNC();
        // setup: b_i = y_mf[i] - (g x)_i, A = I + g diag(var), C = g
        float2 xj = xc_[w][u];
        float vj = vx_[w][u];
        float tr = g_re*xj.x - g_im*xj.y;
        float ti = g_re*xj.y + g_im*xj.x;
        tr += __shfl_xor(tr,1); ti += __shfl_xor(ti,1);
        tr += __shfl_xor(tr,2); ti += __shfl_xor(ti,2);
        tr += __shfl_xor(tr,4); ti += __shfl_xor(ti,4);
        float2 ym = ymc_[w][s];
        float br_ = ym.x - tr, bi_ = ym.y - ti;
        float Ar = g_re*vj + ((s == u) ? 1.f : 0.f);
        float Ai = g_im*vj;
        float Cr = g_re, Ci = g_im;
        // inner unnormalized GJ on [A | b | C], all registers + shuffles
        #pragma unroll
        for (int k = 0; k < 8; ++k) {
            int rowsrc = (k << 3) | u;
            int colsrc = (s << 3) | k;
            float pvr = __shfl(Ar, k * 9);
            float pvi = __shfl(Ai, k * 9);
            float rAr = __shfl(Ar, rowsrc), rAi = __shfl(Ai, rowsrc);
            float rCr = __shfl(Cr, rowsrc), rCi = __shfl(Ci, rowsrc);
            float rbr = __shfl(br_, rowsrc), rbi = __shfl(bi_, rowsrc);
            float cAr = __shfl(Ar, colsrc), cAi = __shfl(Ai, colsrc);
            float id2 = rcpf(pvr*pvr + pvi*pvi);
            float ipr2 = pvr*id2, ipi2 = -pvi*id2;
            float mr2 = cAr*ipr2 - cAi*ipi2;
            float mi2 = cAr*ipi2 + cAi*ipr2;
            if (s == k) { mr2 = 0.f; mi2 = 0.f; }
            Ar  -= mr2*rAr - mi2*rAi;  Ai  -= mr2*rAi + mi2*rAr;
            Cr  -= mr2*rCr - mi2*rCi;  Ci  -= mr2*rCi + mi2*rCr;
            br_ -= mr2*rbr - mi2*rbi;  bi_ -= mr2*rbi + mi2*rbr;
        }
        // extraction on diagonal lanes: z = (w + Cii*x)/mu, no_eff
        if (s == u) {
            float id3 = rcpf(Ar*Ar + Ai*Ai);
            float ipr3 = Ar*id3, ipi3 = -Ai*id3;
            float wr = br_*ipr3 - bi_*ipi3;
            float wi = br_*ipi3 + bi_*ipr3;
            float ccr = Cr*ipr3 - Ci*ipi3;
            float cci = Cr*ipi3 + Ci*ipr3;
            float mu = ccr;
            float im = rcpf(mu);
            float zr = (wr + ccr*xj.x - cci*xj.y) * im;
            float zi = (wi + ccr*xj.y + cci*xj.x) * im;
            xc_[w][s] = make_float2(zr, zi);
            ne_[w][s] = fmaxf(1.f - vx_[w][s]*mu, EPS_F) * im;
        }
        WSYNC();
        // demap: 2 points per lane
        {
            float2 xh = xc_[w][s];
            float idn = rcpf(ne_[w][s]);
            float dr0 = xh.x - pr, dr1 = xh.x + pr, di = xh.y - pi2;
            logit_[w][s][u]     = l0 - (dr0*dr0 + di*di) * idn;
            logit_[w][s][u + 8] = l1 - (dr1*dr1 + di*di) * idn;
        }
        WSYNC();
        // max-log LLR: lane = (s2, bit kb, half); max over 8 matching points
        {
            int s2 = lane >> 3, kb = (lane >> 1) & 3, half = lane & 1;
            int bitpos = 3 - kb;
            float m = -1e30f;
            #pragma unroll
            for (int q = 0; q < 8; ++q) {
                int low  = q & ((1 << bitpos) - 1);
                int high = (q >> bitpos) << (bitpos + 1);
                int p = high | (half << bitpos) | low;
                m = fmaxf(m, logit_[w][s2][p]);
            }
            float other = __shfl_xor(m, 1);
            if (half == 1) llrD_[w][s2][kb] = m - other;   // l1 - l0
        }
        WSYNC();
    }

    if (lane < 32) out[bs*32 + lane] = ((float*)llrD_[w])[lane] - llr_a_reg;
}

extern "C" void kernel_launch(void* const* d_in, const int* in_sizes, int n_in,
                              void* d_out, int out_size, void* d_ws, size_t ws_size,
                              hipStream_t stream) {
    const float* y_re  = (const float*)d_in[0];
    const float* y_im  = (const float*)d_in[1];
    const float* h_re  = (const float*)d_in[2];
    const float* h_im  = (const float*)d_in[3];
    const float* prior = (const float*)d_in[4];
    const float* s_re  = (const float*)d_in[5];
    const float* s_im  = (const float*)d_in[6];
    float* out = (float*)d_out;

    const int B = in_sizes[0] / 16;
    mmse_pic_kernel<<<dim3(B / 2), dim3(128), 0, stream>>>(
        y_re, y_im, h_re, h_im, prior, s_re, s_im, out);
}

// Round 5
// 251.058 us; speedup vs baseline: 1.6654x; 1.6654x over previous
//
#include <hip/hip_runtime.h>

// MMSE-PIC detector: B=32768, M=16, S=8, QAM16 Gray, 2 iterations.
// Round 5: same as round 4 but launch_bounds(128,4) — round 4's (128,8)
// strangled the register allocator to 32 VGPRs and spilled ~20KB/wave to
// scratch (FETCH 55->483MB, WRITE 4KB->656MB). Occupancy comes from LDS
// limit instead: 9728B/block * 16 blocks/CU = 155.6KB <= 160KB -> 32 waves/CU.

#define EPS_F 1e-4f
#define INV_SQRT10 0.31622776601683794f
#define WSYNC() __builtin_amdgcn_wave_barrier()

__device__ __forceinline__ float rcpf(float x) { return __builtin_amdgcn_rcpf(x); }
__device__ __forceinline__ float rsqf(float x) { return __builtin_amdgcn_rsqf(x); }
__device__ __forceinline__ float pt_re(int p) {
    return (1.0f - 2.0f * (float)((p >> 3) & 1)) * (1.0f + 2.0f * (float)((p >> 1) & 1)) * INV_SQRT10;
}
__device__ __forceinline__ float pt_im(int p) {
    return (1.0f - 2.0f * (float)((p >> 2) & 1)) * (1.0f + 2.0f * (float)(p & 1)) * INV_SQRT10;
}

__global__ __launch_bounds__(128, 4)
void mmse_pic_kernel(const float* __restrict__ y_re, const float* __restrict__ y_im,
                     const float* __restrict__ h_re, const float* __restrict__ h_im,
                     const float* __restrict__ prior,
                     const float* __restrict__ s_re, const float* __restrict__ s_im,
                     float* __restrict__ out)
{
    const int lane = threadIdx.x & 63;
    const int w    = threadIdx.x >> 6;            // wave id in block = sub-batch
    const int b    = blockIdx.x * 2 + w;
    const size_t bs = (size_t)b;

    __shared__ float2 Sc[2][16][28];   // [S(0-15) | h(16-23) | y(24)] -> W after elim+scale
    __shared__ float2 xc_[2][8];
    __shared__ float2 ymc_[2][8];
    __shared__ float  vx_[2][8], ne_[2][8];
    __shared__ float  lsig[2][64];
    __shared__ float  logit_[2][8][20];
    __shared__ float  llrD_[2][8][4];

    // ---- load (vectorized, interleave re/im into float2) ----
    {
        const float4* pr4 = (const float4*)(s_re + bs * 256);
        const float4* pi4 = (const float4*)(s_im + bs * 256);
        float4 vr = pr4[lane], vi = pi4[lane];
        int r = lane >> 2, c0 = (lane & 3) << 2;
        Sc[w][r][c0+0] = make_float2(vr.x, vi.x);
        Sc[w][r][c0+1] = make_float2(vr.y, vi.y);
        Sc[w][r][c0+2] = make_float2(vr.z, vi.z);
        Sc[w][r][c0+3] = make_float2(vr.w, vi.w);
        if (lane < 32) {
            const float4* hr4 = (const float4*)(h_re + bs * 128);
            const float4* hi4 = (const float4*)(h_im + bs * 128);
            float4 hr = hr4[lane], hi = hi4[lane];
            int row = lane >> 1, col = 16 + ((lane & 1) << 2);
            Sc[w][row][col+0] = make_float2(hr.x, hi.x);
            Sc[w][row][col+1] = make_float2(hr.y, hi.y);
            Sc[w][row][col+2] = make_float2(hr.z, hi.z);
            Sc[w][row][col+3] = make_float2(hr.w, hi.w);
        }
        if (lane < 16) Sc[w][lane][24] = make_float2(y_re[bs*16+lane], y_im[bs*16+lane]);
        if (lane < 32) ((float*)llrD_[w])[lane] = prior[bs*32 + lane];
    }
    WSYNC();

    // ---- forward-only unnormalized elimination on [S | h y] ----
    // After step k, rows i>k: row_i -= (S[i][k]/d_k) row_k  (cols k+1..24).
    // RHS rows become L^-1 [h|y]; pivots d_k real (S HPD).
    {
        const int j0 = lane & 15;
        const int r4 = lane >> 4;
        for (int k = 0; k < 15; ++k) {
            float invd = rcpf(Sc[w][k][k].x);
            int j1 = k + 1 + j0, j2 = j1 + 16;
            float2 rk0 = make_float2(0.f, 0.f), rk1 = make_float2(0.f, 0.f);
            if (j1 < 25) rk0 = Sc[w][k][j1];
            const bool blk2 = (k < 8);
            if (blk2 && j2 < 25) rk1 = Sc[w][k][j2];
            const int pmin = (k + 1) >> 2;          // skip row-blocks entirely <= k
            for (int p = pmin; p < 4; ++p) {
                int i = (p << 2) + r4;
                float2 aik = Sc[w][i][k];
                float mr = aik.x * invd, mi = aik.y * invd;
                if (i <= k) { mr = 0.f; mi = 0.f; }
                if (j1 < 25) {
                    float2 a = Sc[w][i][j1];
                    a.x -= mr*rk0.x - mi*rk0.y;
                    a.y -= mr*rk0.y + mi*rk0.x;
                    Sc[w][i][j1] = a;
                }
                if (blk2 && j2 < 25) {
                    float2 a = Sc[w][i][j2];
                    a.x -= mr*rk1.x - mi*rk1.y;
                    a.y -= mr*rk1.y + mi*rk1.x;
                    Sc[w][i][j2] = a;
                }
            }
            WSYNC();
        }
    }
    // ---- scale RHS rows by rsqrt(d_m): W = D^-1/2 L^-1 [h|y] (= whitened) ----
    {
        int r2 = lane >> 2, c = lane & 3;
        float irs = rsqf(Sc[w][r2][r2].x);
        float2 v0 = Sc[w][r2][16 + c];
        Sc[w][r2][16 + c] = make_float2(v0.x*irs, v0.y*irs);
        float2 v1 = Sc[w][r2][20 + c];
        Sc[w][r2][20 + c] = make_float2(v1.x*irs, v1.y*irs);
        if (c == 0) {
            float2 v2 = Sc[w][r2][24];
            Sc[w][r2][24] = make_float2(v2.x*irs, v2.y*irs);
        }
    }
    WSYNC();

    // ---- Gram g[i][j] = (Wh^H Wh)[i][j] (1 entry/lane), y_mf = Wh^H Wy ----
    const int s = lane >> 3, u = lane & 7;
    float g_re = 0.f, g_im = 0.f, ym_r = 0.f, ym_i = 0.f;
    #pragma unroll
    for (int m = 0; m < 16; ++m) {
        float2 a  = Sc[w][m][16 + s];
        float2 x  = Sc[w][m][16 + u];
        float2 xy = Sc[w][m][24];
        g_re += a.x*x.x + a.y*x.y;      // conj(a)*x
        g_im += a.x*x.y - a.y*x.x;
        ym_r += a.x*xy.x + a.y*xy.y;
        ym_i += a.x*xy.y - a.y*xy.x;
    }
    if (u == 0) ymc_[w][s] = make_float2(ym_r, ym_i);
    WSYNC();

    const float pr = pt_re(u), pi2 = pt_im(u), pe = pr*pr + pi2*pi2;  // pt(u+8) = (-pr, pi2)
    float llr_a_reg = 0.f;

    for (int it = 0; it < 2; ++it) {
        // log-sigmoid table: one distinct value per lane
        {
            int ts = lane >> 3, tk = (lane >> 1) & 3, sg = lane & 1;
            float v = llrD_[w][ts][tk];
            float x = sg ? v : -v;
            lsig[w][lane] = fminf(x, 0.f) - __logf(1.0f + __expf(-fabsf(x)));
        }
        if (lane < 32) llr_a_reg = ((float*)llrD_[w])[lane];
        WSYNC();
        // symbol logits for p=u (l0) and p=u+8 (l1), in registers
        int base = s << 3;
        float lc = lsig[w][base | 2 | ((u >> 2) & 1)]
                 + lsig[w][base | 4 | ((u >> 1) & 1)]
                 + lsig[w][base | 6 | (u & 1)];
        float l0 = lc + lsig[w][base];
        float l1 = lc + lsig[w][base | 1];
        // moments: butterfly over the 8 lanes of stream s
        {
            float mx = fmaxf(l0, l1);
            mx = fmaxf(mx, __shfl_xor(mx, 1));
            mx = fmaxf(mx, __shfl_xor(mx, 2));
            mx = fmaxf(mx, __shfl_xor(mx, 4));
            float w0 = __expf(l0 - mx), w1 = __expf(l1 - mx);
            float a = w0 + w1, dw = w0 - w1;
            float se = a, mr = dw * pr, mi = a * pi2, e2 = a * pe;
            se += __shfl_xor(se,1); mr += __shfl_xor(mr,1); mi += __shfl_xor(mi,1); e2 += __shfl_xor(e2,1);
            se += __shfl_xor(se,2); mr += __shfl_xor(mr,2); mi += __shfl_xor(mi,2); e2 += __shfl_xor(e2,2);
            se += __shfl_xor(se,4); mr += __shfl_xor(mr,4); mi += __shfl_xor(mi,4); e2 += __shfl_xor(e2,4);
            if (u == 0) {
                float inv = rcpf(se);
                float mxr = mr*inv, mxi = mi*inv;
                xc_[w][s] = make_float2(mxr, mxi);
                vx_[w][s] = e2*inv - (mxr*mxr + mxi*mxi);
            }
        }
        WSYNC();
        // setup: b_i = y_mf[i] - (g x)_i, A = I + g diag(var), C = g
        float2 xj = xc_[w][u];
        float vj = vx_[w][u];
        float tr = g_re*xj.x - g_im*xj.y;
        float ti = g_re*xj.y + g_im*xj.x;
        tr += __shfl_xor(tr,1); ti += __shfl_xor(ti,1);
        tr += __shfl_xor(tr,2); ti += __shfl_xor(ti,2);
        tr += __shfl_xor(tr,4); ti += __shfl_xor(ti,4);
        float2 ym = ymc_[w][s];
        float br_ = ym.x - tr, bi_ = ym.y - ti;
        float Ar = g_re*vj + ((s == u) ? 1.f : 0.f);
        float Ai = g_im*vj;
        float Cr = g_re, Ci = g_im;
        // inner unnormalized GJ on [A | b | C], all registers + shuffles
        #pragma unroll
        for (int k = 0; k < 8; ++k) {
            int rowsrc = (k << 3) | u;
            int colsrc = (s << 3) | k;
            float pvr = __shfl(Ar, k * 9);
            float pvi = __shfl(Ai, k * 9);
            float rAr = __shfl(Ar, rowsrc), rAi = __shfl(Ai, rowsrc);
            float rCr = __shfl(Cr, rowsrc), rCi = __shfl(Ci, rowsrc);
            float rbr = __shfl(br_, rowsrc), rbi = __shfl(bi_, rowsrc);
            float cAr = __shfl(Ar, colsrc), cAi = __shfl(Ai, colsrc);
            float id2 = rcpf(pvr*pvr + pvi*pvi);
            float ipr2 = pvr*id2, ipi2 = -pvi*id2;
            float mr2 = cAr*ipr2 - cAi*ipi2;
            float mi2 = cAr*ipi2 + cAi*ipr2;
            if (s == k) { mr2 = 0.f; mi2 = 0.f; }
            Ar  -= mr2*rAr - mi2*rAi;  Ai  -= mr2*rAi + mi2*rAr;
            Cr  -= mr2*rCr - mi2*rCi;  Ci  -= mr2*rCi + mi2*rCr;
            br_ -= mr2*rbr - mi2*rbi;  bi_ -= mr2*rbi + mi2*rbr;
        }
        // extraction on diagonal lanes: z = (w + Cii*x)/mu, no_eff
        if (s == u) {
            float id3 = rcpf(Ar*Ar + Ai*Ai);
            float ipr3 = Ar*id3, ipi3 = -Ai*id3;
            float wr = br_*ipr3 - bi_*ipi3;
            float wi = br_*ipi3 + bi_*ipr3;
            float ccr = Cr*ipr3 - Ci*ipi3;
            float cci = Cr*ipi3 + Ci*ipr3;
            float mu = ccr;
            float im = rcpf(mu);
            float zr = (wr + ccr*xj.x - cci*xj.y) * im;
            float zi = (wi + ccr*xj.y + cci*xj.x) * im;
            xc_[w][s] = make_float2(zr, zi);
            ne_[w][s] = fmaxf(1.f - vx_[w][s]*mu, EPS_F) * im;
        }
        WSYNC();
        // demap: 2 points per lane
        {
            float2 xh = xc_[w][s];
            float idn = rcpf(ne_[w][s]);
            float dr0 = xh.x - pr, dr1 = xh.x + pr, di = xh.y - pi2;
            logit_[w][s][u]     = l0 - (dr0*dr0 + di*di) * idn;
            logit_[w][s][u + 8] = l1 - (dr1*dr1 + di*di) * idn;
        }
        WSYNC();
        // max-log LLR: lane = (s2, bit kb, half); max over 8 matching points
        {
            int s2 = lane >> 3, kb = (lane >> 1) & 3, half = lane & 1;
            int bitpos = 3 - kb;
            float m = -1e30f;
            #pragma unroll
            for (int q = 0; q < 8; ++q) {
                int low  = q & ((1 << bitpos) - 1);
                int high = (q >> bitpos) << (bitpos + 1);
                int p = high | (half << bitpos) | low;
                m = fmaxf(m, logit_[w][s2][p]);
            }
            float other = __shfl_xor(m, 1);
            if (half == 1) llrD_[w][s2][kb] = m - other;   // l1 - l0
        }
        WSYNC();
    }

    if (lane < 32) out[bs*32 + lane] = ((float*)llrD_[w])[lane] - llr_a_reg;
}

extern "C" void kernel_launch(void* const* d_in, const int* in_sizes, int n_in,
                              void* d_out, int out_size, void* d_ws, size_t ws_size,
                              hipStream_t stream) {
    const float* y_re  = (const float*)d_in[0];
    const float* y_im  = (const float*)d_in[1];
    const float* h_re  = (const float*)d_in[2];
    const float* h_im  = (const float*)d_in[3];
    const float* prior = (const float*)d_in[4];
    const float* s_re  = (const float*)d_in[5];
    const float* s_im  = (const float*)d_in[6];
    float* out = (float*)d_out;

    const int B = in_sizes[0] / 16;
    mmse_pic_kernel<<<dim3(B / 2), dim3(128), 0, stream>>>(
        y_re, y_im, h_re, h_im, prior, s_re, s_im, out);
}

// Round 6
// 234.157 us; speedup vs baseline: 1.7856x; 1.0722x over previous
//
#include <hip/hip_runtime.h>

// MMSE-PIC detector: B=32768, M=16, S=8, QAM16 Gray, 2 iterations.
// Round 6: instruction-fat reduction. Fully unrolled outer elimination
// (scalar/addr math folds to immediates), v_readlane pivot broadcast +
// ds_swizzle multiplier broadcast in the register inner solve, ds_swizzle
// immediates for all xor-butterflies (no bpermute index setup).

#define EPS_F 1e-4f
#define INV_SQRT10 0.31622776601683794f
#define WSYNC() __builtin_amdgcn_wave_barrier()

__device__ __forceinline__ float rcpf(float x) { return __builtin_amdgcn_rcpf(x); }
__device__ __forceinline__ float rsqf(float x) { return __builtin_amdgcn_rsqf(x); }
__device__ __forceinline__ float rdlane(float v, int l) {
    return __uint_as_float(__builtin_amdgcn_readlane(__float_as_uint(v), l));
}
template<int OFF>
__device__ __forceinline__ float swzf(float v) {
    return __uint_as_float(__builtin_amdgcn_ds_swizzle(__float_as_uint(v), OFF));
}
// xor-butterfly swizzle patterns (BitMode: offset = xor<<10 | or<<5 | and)
#define SWX1 0x041F
#define SWX2 0x081F
#define SWX4 0x101F

__device__ __forceinline__ float pt_re(int p) {
    return (1.0f - 2.0f * (float)((p >> 3) & 1)) * (1.0f + 2.0f * (float)((p >> 1) & 1)) * INV_SQRT10;
}
__device__ __forceinline__ float pt_im(int p) {
    return (1.0f - 2.0f * (float)((p >> 2) & 1)) * (1.0f + 2.0f * (float)(p & 1)) * INV_SQRT10;
}

__global__ __launch_bounds__(128, 4)
void mmse_pic_kernel(const float* __restrict__ y_re, const float* __restrict__ y_im,
                     const float* __restrict__ h_re, const float* __restrict__ h_im,
                     const float* __restrict__ prior,
                     const float* __restrict__ s_re, const float* __restrict__ s_im,
                     float* __restrict__ out)
{
    const int lane = threadIdx.x & 63;
    const int w    = threadIdx.x >> 6;            // wave id in block = sub-batch
    const int b    = blockIdx.x * 2 + w;
    const size_t bs = (size_t)b;

    __shared__ float2 Sc[2][16][28];   // [S(0-15) | h(16-23) | y(24)] -> W after elim+scale
    __shared__ float2 xc_[2][8];
    __shared__ float2 ymc_[2][8];
    __shared__ float  vx_[2][8], ne_[2][8];
    __shared__ float  lsig[2][64];
    __shared__ float  logit_[2][8][20];
    __shared__ float  llrD_[2][8][4];

    // ---- load (vectorized, interleave re/im into float2) ----
    {
        const float4* pr4 = (const float4*)(s_re + bs * 256);
        const float4* pi4 = (const float4*)(s_im + bs * 256);
        float4 vr = pr4[lane], vi = pi4[lane];
        int r = lane >> 2, c0 = (lane & 3) << 2;
        Sc[w][r][c0+0] = make_float2(vr.x, vi.x);
        Sc[w][r][c0+1] = make_float2(vr.y, vi.y);
        Sc[w][r][c0+2] = make_float2(vr.z, vi.z);
        Sc[w][r][c0+3] = make_float2(vr.w, vi.w);
        if (lane < 32) {
            const float4* hr4 = (const float4*)(h_re + bs * 128);
            const float4* hi4 = (const float4*)(h_im + bs * 128);
            float4 hr = hr4[lane], hi = hi4[lane];
            int row = lane >> 1, col = 16 + ((lane & 1) << 2);
            Sc[w][row][col+0] = make_float2(hr.x, hi.x);
            Sc[w][row][col+1] = make_float2(hr.y, hi.y);
            Sc[w][row][col+2] = make_float2(hr.z, hi.z);
            Sc[w][row][col+3] = make_float2(hr.w, hi.w);
        }
        if (lane < 16) Sc[w][lane][24] = make_float2(y_re[bs*16+lane], y_im[bs*16+lane]);
        if (lane < 32) ((float*)llrD_[w])[lane] = prior[bs*32 + lane];
    }
    WSYNC();

    // ---- forward-only unnormalized elimination on [S | h y] (fully unrolled) ----
    {
        const int j0 = lane & 15;
        const int r4 = lane >> 4;
        #pragma unroll
        for (int k = 0; k < 15; ++k) {
            float invd = rcpf(Sc[w][k][k].x);
            int j1 = k + 1 + j0, j2 = j1 + 16;
            float2 rk0 = make_float2(0.f, 0.f), rk1 = make_float2(0.f, 0.f);
            if (j1 < 25) rk0 = Sc[w][k][j1];
            const bool blk2 = (k < 8);
            if (blk2 && j2 < 25) rk1 = Sc[w][k][j2];
            const int pmin = (k + 1) >> 2;          // compile-time per unrolled k
            #pragma unroll
            for (int p = 0; p < 4; ++p) {
                if (p < pmin) continue;
                int i = (p << 2) + r4;
                float2 aik = Sc[w][i][k];
                float mr = aik.x * invd, mi = aik.y * invd;
                if (i <= k) { mr = 0.f; mi = 0.f; }
                if (j1 < 25) {
                    float2 a = Sc[w][i][j1];
                    a.x -= mr*rk0.x - mi*rk0.y;
                    a.y -= mr*rk0.y + mi*rk0.x;
                    Sc[w][i][j1] = a;
                }
                if (blk2 && j2 < 25) {
                    float2 a = Sc[w][i][j2];
                    a.x -= mr*rk1.x - mi*rk1.y;
                    a.y -= mr*rk1.y + mi*rk1.x;
                    Sc[w][i][j2] = a;
                }
            }
            WSYNC();
        }
    }
    // ---- scale RHS rows by rsqrt(d_m): W = D^-1/2 L^-1 [h|y] (= whitened) ----
    {
        int r2 = lane >> 2, c = lane & 3;
        float irs = rsqf(Sc[w][r2][r2].x);
        float2 v0 = Sc[w][r2][16 + c];
        Sc[w][r2][16 + c] = make_float2(v0.x*irs, v0.y*irs);
        float2 v1 = Sc[w][r2][20 + c];
        Sc[w][r2][20 + c] = make_float2(v1.x*irs, v1.y*irs);
        if (c == 0) {
            float2 v2 = Sc[w][r2][24];
            Sc[w][r2][24] = make_float2(v2.x*irs, v2.y*irs);
        }
    }
    WSYNC();

    // ---- Gram g[i][j] = (Wh^H Wh)[i][j] (1 entry/lane), y_mf = Wh^H Wy ----
    const int s = lane >> 3, u = lane & 7;
    float g_re = 0.f, g_im = 0.f, ym_r = 0.f, ym_i = 0.f;
    #pragma unroll
    for (int m = 0; m < 16; ++m) {
        float2 a  = Sc[w][m][16 + s];
        float2 x  = Sc[w][m][16 + u];
        float2 xy = Sc[w][m][24];
        g_re += a.x*x.x + a.y*x.y;      // conj(a)*x
        g_im += a.x*x.y - a.y*x.x;
        ym_r += a.x*xy.x + a.y*xy.y;
        ym_i += a.x*xy.y - a.y*xy.x;
    }
    if (u == 0) ymc_[w][s] = make_float2(ym_r, ym_i);
    WSYNC();

    const float pr = pt_re(u), pi2 = pt_im(u), pe = pr*pr + pi2*pi2;  // pt(u+8) = (-pr, pi2)
    float llr_a_reg = 0.f;

    for (int it = 0; it < 2; ++it) {
        // log-sigmoid table: one distinct value per lane
        {
            int ts = lane >> 3, tk = (lane >> 1) & 3, sg = lane & 1;
            float v = llrD_[w][ts][tk];
            float x = sg ? v : -v;
            lsig[w][lane] = fminf(x, 0.f) - __logf(1.0f + __expf(-fabsf(x)));
        }
        if (lane < 32) llr_a_reg = ((float*)llrD_[w])[lane];
        WSYNC();
        // symbol logits for p=u (l0) and p=u+8 (l1), in registers
        int base = s << 3;
        float lc = lsig[w][base | 2 | ((u >> 2) & 1)]
                 + lsig[w][base | 4 | ((u >> 1) & 1)]
                 + lsig[w][base | 6 | (u & 1)];
        float l0 = lc + lsig[w][base];
        float l1 = lc + lsig[w][base | 1];
        // moments: swizzle-butterfly over the 8 lanes of stream s
        {
            float mx = fmaxf(l0, l1);
            mx = fmaxf(mx, swzf<SWX1>(mx));
            mx = fmaxf(mx, swzf<SWX2>(mx));
            mx = fmaxf(mx, swzf<SWX4>(mx));
            float w0 = __expf(l0 - mx), w1 = __expf(l1 - mx);
            float a = w0 + w1, dw = w0 - w1;
            float se = a, mr = dw * pr, mi = a * pi2, e2 = a * pe;
            se += swzf<SWX1>(se); mr += swzf<SWX1>(mr); mi += swzf<SWX1>(mi); e2 += swzf<SWX1>(e2);
            se += swzf<SWX2>(se); mr += swzf<SWX2>(mr); mi += swzf<SWX2>(mi); e2 += swzf<SWX2>(e2);
            se += swzf<SWX4>(se); mr += swzf<SWX4>(mr); mi += swzf<SWX4>(mi); e2 += swzf<SWX4>(e2);
            if (u == 0) {
                float inv = rcpf(se);
                float mxr = mr*inv, mxi = mi*inv;
                xc_[w][s] = make_float2(mxr, mxi);
                vx_[w][s] = e2*inv - (mxr*mxr + mxi*mxi);
            }
        }
        WSYNC();
        // setup: b_i = y_mf[i] - (g x)_i, A = I + g diag(var), C = g
        float2 xj = xc_[w][u];
        float vj = vx_[w][u];
        float tr = g_re*xj.x - g_im*xj.y;
        float ti = g_re*xj.y + g_im*xj.x;
        tr += swzf<SWX1>(tr); ti += swzf<SWX1>(ti);
        tr += swzf<SWX2>(tr); ti += swzf<SWX2>(ti);
        tr += swzf<SWX4>(tr); ti += swzf<SWX4>(ti);
        float2 ym = ymc_[w][s];
        float br_ = ym.x - tr, bi_ = ym.y - ti;
        float Ar = g_re*vj + ((s == u) ? 1.f : 0.f);
        float Ai = g_im*vj;
        float Cr = g_re, Ci = g_im;
        // inner unnormalized GJ on [A | b | C]: registers; pivot via v_readlane
        // (uniform), multiplier bcast via ds_swizzle (src=(L&0x38)|K), row bcast
        // via bpermute.
        #define GJ_STEP(K) { \
            float pvr = rdlane(Ar, (K)*9), pvi = rdlane(Ai, (K)*9); \
            int rowsrc = ((K)<<3)|u; \
            float rAr = __shfl(Ar, rowsrc), rAi = __shfl(Ai, rowsrc); \
            float rCr = __shfl(Cr, rowsrc), rCi = __shfl(Ci, rowsrc); \
            float rbr = __shfl(br_, rowsrc), rbi = __shfl(bi_, rowsrc); \
            float cAr = swzf<(((K)<<5)|0x18)>(Ar), cAi = swzf<(((K)<<5)|0x18)>(Ai); \
            float id2 = rcpf(pvr*pvr + pvi*pvi); \
            float ipr2 = pvr*id2, ipi2 = -pvi*id2; \
            float mr2 = cAr*ipr2 - cAi*ipi2; \
            float mi2 = cAr*ipi2 + cAi*ipr2; \
            if (s == (K)) { mr2 = 0.f; mi2 = 0.f; } \
            Ar  -= mr2*rAr - mi2*rAi;  Ai  -= mr2*rAi + mi2*rAr; \
            Cr  -= mr2*rCr - mi2*rCi;  Ci  -= mr2*rCi + mi2*rCr; \
            br_ -= mr2*rbr - mi2*rbi;  bi_ -= mr2*rbi + mi2*rbr; }
        GJ_STEP(0) GJ_STEP(1) GJ_STEP(2) GJ_STEP(3)
        GJ_STEP(4) GJ_STEP(5) GJ_STEP(6) GJ_STEP(7)
        #undef GJ_STEP
        // extraction on diagonal lanes: z = (w + Cii*x)/mu, no_eff
        if (s == u) {
            float id3 = rcpf(Ar*Ar + Ai*Ai);
            float ipr3 = Ar*id3, ipi3 = -Ai*id3;
            float wr = br_*ipr3 - bi_*ipi3;
            float wi = br_*ipi3 + bi_*ipr3;
            float ccr = Cr*ipr3 - Ci*ipi3;
            float cci = Cr*ipi3 + Ci*ipr3;
            float mu = ccr;
            float im = rcpf(mu);
            float zr = (wr + ccr*xj.x - cci*xj.y) * im;
            float zi = (wi + ccr*xj.y + cci*xj.x) * im;
            xc_[w][s] = make_float2(zr, zi);
            ne_[w][s] = fmaxf(1.f - vx_[w][s]*mu, EPS_F) * im;
        }
        WSYNC();
        // demap: 2 points per lane
        {
            float2 xh = xc_[w][s];
            float idn = rcpf(ne_[w][s]);
            float dr0 = xh.x - pr, dr1 = xh.x + pr, di = xh.y - pi2;
            logit_[w][s][u]     = l0 - (dr0*dr0 + di*di) * idn;
            logit_[w][s][u + 8] = l1 - (dr1*dr1 + di*di) * idn;
        }
        WSYNC();
        // max-log LLR: lane = (s2, bit kb, half); max over 8 matching points
        {
            int s2 = lane >> 3, kb = (lane >> 1) & 3, half = lane & 1;
            int bitpos = 3 - kb;
            float m = -1e30f;
            #pragma unroll
            for (int q = 0; q < 8; ++q) {
                int low  = q & ((1 << bitpos) - 1);
                int high = (q >> bitpos) << (bitpos + 1);
                int p = high | (half << bitpos) | low;
                m = fmaxf(m, logit_[w][s2][p]);
            }
            float other = swzf<SWX1>(m);
            if (half == 1) llrD_[w][s2][kb] = m - other;   // l1 - l0
        }
        WSYNC();
    }

    if (lane < 32) out[bs*32 + lane] = ((float*)llrD_[w])[lane] - llr_a_reg;
}

extern "C" void kernel_launch(void* const* d_in, const int* in_sizes, int n_in,
                              void* d_out, int out_size, void* d_ws, size_t ws_size,
                              hipStream_t stream) {
    const float* y_re  = (const float*)d_in[0];
    const float* y_im  = (const float*)d_in[1];
    const float* h_re  = (const float*)d_in[2];
    const float* h_im  = (const float*)d_in[3];
    const float* prior = (const float*)d_in[4];
    const float* s_re  = (const float*)d_in[5];
    const float* s_im  = (const float*)d_in[6];
    float* out = (float*)d_out;

    const int B = in_sizes[0] / 16;
    mmse_pic_kernel<<<dim3(B / 2), dim3(128), 0, stream>>>(
        y_re, y_im, h_re, h_im, prior, s_re, s_im, out);
}